// Round 5
// baseline (27720.499 us; speedup 1.0000x reference)
//
#include <hip/hip_runtime.h>
#include <cstdint>

typedef unsigned long long ull;

#define B_ 4
#define N_ 16384
#define C_ 64
#define O_ 128
#define S_ 4096
#define K_ 32
#define CK_ 67  // C+3

// ---------------------------------------------------------------------------
// Counting sort by 16^3 Morton cell (UNCHANGED from round 4 -- verified).
// ---------------------------------------------------------------------------
__device__ __forceinline__ unsigned part3_4(unsigned v) {
  return (v & 1u) | ((v & 2u) << 2) | ((v & 4u) << 4) | ((v & 8u) << 6);
}

__launch_bounds__(1024, 1)
__global__ void sort_kernel(const float* __restrict__ xyz,
                            float4* __restrict__ sorted) {
  const int b = blockIdx.x, t = threadIdx.x;
  const int lane = t & 63, wid = t >> 6;
  __shared__ unsigned hist[4096];
  __shared__ unsigned wsum[16];
  for (int i = t; i < 4096; i += 1024) hist[i] = 0u;
  __syncthreads();
  const float* base = xyz + (size_t)b * N_ * 3;
  int cell[16];
#pragma unroll
  for (int j = 0; j < 16; ++j) {
    int p = j * 1024 + t;
    float x = base[p * 3 + 0], y = base[p * 3 + 1], z = base[p * 3 + 2];
    int cx = (int)floorf((x + 6.0f) * (16.0f / 12.0f));
    int cy = (int)floorf((y + 6.0f) * (16.0f / 12.0f));
    int cz = (int)floorf((z + 6.0f) * (16.0f / 12.0f));
    cx = min(max(cx, 0), 15); cy = min(max(cy, 0), 15); cz = min(max(cz, 0), 15);
    int m = (int)(part3_4((unsigned)cx) | (part3_4((unsigned)cy) << 1) |
                  (part3_4((unsigned)cz) << 2));
    cell[j] = m;
    atomicAdd(&hist[m], 1u);
  }
  __syncthreads();
  unsigned h0 = hist[4 * t + 0], h1 = hist[4 * t + 1];
  unsigned h2 = hist[4 * t + 2], h3 = hist[4 * t + 3];
  unsigned s4 = h0 + h1 + h2 + h3;
  unsigned inc = s4;
#pragma unroll
  for (int off = 1; off < 64; off <<= 1) {
    unsigned n = __shfl_up(inc, off);
    if (lane >= off) inc += n;
  }
  if (lane == 63) wsum[wid] = inc;
  __syncthreads();
  if (t < 16) {
    unsigned v = wsum[t], iv = v;
#pragma unroll
    for (int off = 1; off < 16; off <<= 1) {
      unsigned n = __shfl_up(iv, off);
      if (t >= off) iv += n;
    }
    wsum[t] = iv - v;
  }
  __syncthreads();
  unsigned st = wsum[wid] + (inc - s4);
  hist[4 * t + 0] = st;
  hist[4 * t + 1] = st + h0;
  hist[4 * t + 2] = st + h0 + h1;
  hist[4 * t + 3] = st + h0 + h1 + h2;
  __syncthreads();
#pragma unroll
  for (int j = 0; j < 16; ++j) {
    int p = j * 1024 + t;
    float x = base[p * 3 + 0], y = base[p * 3 + 1], z = base[p * 3 + 2];
    unsigned pos = atomicAdd(&hist[cell[j]], 1u);
    float4 o;
    o.x = x; o.y = y; o.z = z; o.w = __uint_as_float((unsigned)p);
    sorted[(size_t)b * N_ + pos] = o;
  }
}

// ---------------------------------------------------------------------------
// FPS v4: 1024 threads x 16 pts (all state in regs, ~100 VGPR < 128 cap).
// WAVE-uniform lazy skip: wave executes the update only if __any lane's
// AABB lower-bound can beat its bucket max. Skipped wave forwards its previous
// candidate (key+coords) across the double buffer — exact, since its dists are
// untouched. Winner's region always has lb=0 -> forced update.
// Distance expr byte-identical to verified rounds. Key = dist|~og|pos exact.
// Wave 0 alone does the final 16-slot reduce; coords broadcast via LDS.
// ---------------------------------------------------------------------------
__launch_bounds__(1024, 4)
__global__ void fps_kernel(const float* __restrict__ xyz,
                           const float4* __restrict__ sorted,
                           float* __restrict__ new_xyz) {
#pragma clang fp contract(off)
  const int b = blockIdx.x, t = threadIdx.x;
  const int lane = t & 63, wid = t >> 6;  // 16 waves
  const float4* sb = sorted + (size_t)b * N_;
  float px[16], py[16], pz[16], dist[16];
  unsigned po2[8];
#pragma unroll
  for (int j = 0; j < 16; ++j) {
    float4 v = sb[16 * t + j];
    px[j] = v.x; py[j] = v.y; pz[j] = v.z;
    dist[j] = 1e10f;
    unsigned o = __float_as_uint(v.w);
    if ((j & 1) == 0) po2[j >> 1] = o; else po2[j >> 1] |= (o << 16);
  }
  float lox = px[0], hix = px[0], loy = py[0], hiy = py[0], loz = pz[0], hiz = pz[0];
#pragma unroll
  for (int j = 1; j < 16; ++j) {
    lox = fminf(lox, px[j]); hix = fmaxf(hix, px[j]);
    loy = fminf(loy, py[j]); hiy = fmaxf(hiy, py[j]);
    loz = fminf(loz, pz[j]); hiz = fmaxf(hiz, pz[j]);
  }
  __shared__ ull s_key[2][16];
  __shared__ float s_cd[2][16][3];
  __shared__ float s_c[2][3];
  const float* ob = xyz + (size_t)b * N_ * 3;
  float fx = ob[0], fy = ob[1], fz = ob[2];  // far = 0 initially
  ull mykey = ((ull)__float_as_uint(1e10f)) << 28;  // bmax=1e10: no skip at s=0
  for (int s = 0; s < S_; ++s) {
    const int buf = s & 1;
    if (t == 0) {
      float* o = new_xyz + ((size_t)b * S_ + s) * 3;
      o[0] = fx; o[1] = fy; o[2] = fz;
    }
    float dxm = fmaxf(fmaxf(lox - fx, fx - hix), 0.0f);
    float dym = fmaxf(fmaxf(loy - fy, fy - hiy), 0.0f);
    float dzm = fmaxf(fmaxf(loz - fz, fz - hiz), 0.0f);
    float lb = dxm * dxm + dym * dym + dzm * dzm;
    float bmax = __uint_as_float((unsigned)(mykey >> 28));
    bool need = (lb * 0.99998f < bmax);  // conservative: covers f32 rounding
    if (__any(need)) {
      // whole wave updates (re-updating a skippable lane is a numeric no-op)
      float bv = -1.0f;
      unsigned bo = 0xFFFFFFFFu;
      int bp = 0;
      float bx = px[0], by = py[0], bz = pz[0];
#pragma unroll
      for (int j = 0; j < 16; ++j) {
        float dx = px[j] - fx;
        float dy = py[j] - fy;
        float dz = pz[j] - fz;
        float d = dx * dx + dy * dy + dz * dz;  // contract off, verified form
        float m = fminf(dist[j], d);
        dist[j] = m;
        unsigned og = (po2[j >> 1] >> (16 * (j & 1))) & 0xFFFFu;
        bool better = (m > bv) || ((m == bv) && (og < bo));
        if (better) { bv = m; bo = og; bp = j; bx = px[j]; by = py[j]; bz = pz[j]; }
      }
      mykey = (((ull)__float_as_uint(bv)) << 28) |
              (((ull)((~bo) & 0x3FFFu)) << 14) | (unsigned)(16 * t + bp);
      ull k = mykey;
#pragma unroll
      for (int off = 1; off < 64; off <<= 1) {
        ull o = __shfl_xor(k, off);
        if (o > k) k = o;
      }
      if (k == mykey) {  // exactly one lane (pos bits unique)
        s_key[buf][wid] = k;
        s_cd[buf][wid][0] = bx; s_cd[buf][wid][1] = by; s_cd[buf][wid][2] = bz;
      }
    } else {
      if (lane == 0) {  // forward previous candidate (dists untouched -> exact)
        s_key[buf][wid] = s_key[buf ^ 1][wid];
        s_cd[buf][wid][0] = s_cd[buf ^ 1][wid][0];
        s_cd[buf][wid][1] = s_cd[buf ^ 1][wid][1];
        s_cd[buf][wid][2] = s_cd[buf ^ 1][wid][2];
      }
    }
    __syncthreads();
    if (wid == 0) {
      ull kb = s_key[buf][0];
      int bw = 0;
#pragma unroll
      for (int w = 1; w < 16; ++w) {
        ull o = s_key[buf][w];
        if (o > kb) { kb = o; bw = w; }
      }
      if (lane == 0) {
        s_c[buf][0] = s_cd[buf][bw][0];
        s_c[buf][1] = s_cd[buf][bw][1];
        s_c[buf][2] = s_cd[buf][bw][2];
      }
    }
    __syncthreads();
    fx = s_c[buf][0]; fy = s_c[buf][1]; fz = s_c[buf][2];
  }
}

// ---------------------------------------------------------------------------
// KNN over new_xyz (UNCHANGED -- verified).
// ---------------------------------------------------------------------------
__launch_bounds__(256, 2)
__global__ void knn_kernel(const float* __restrict__ new_xyz,
                           int* __restrict__ knn_idx) {
  const int b = blockIdx.y;
  const int t = threadIdx.x;
  const int q = blockIdx.x * 256 + t;
  __shared__ float sx[S_], sy[S_], sz[S_], sn[S_];
  const float* nb = new_xyz + (size_t)b * S_ * 3;
  for (int i = t; i < S_; i += 256) {
    float x = nb[i * 3 + 0], y = nb[i * 3 + 1], z = nb[i * 3 + 2];
    sx[i] = x; sy[i] = y; sz[i] = z;
    sn[i] = fmaf(z, z, fmaf(y, y, x * x));
  }
  __syncthreads();
  const float qx = sx[q], qy = sy[q], qz = sz[q], qn = sn[q];
  unsigned long long kv[K_];
#pragma unroll
  for (int j = 0; j < K_; ++j) kv[j] = 0ull;
  for (int i = 0; i < S_; ++i) {
    float inner = fmaf(sz[i], qz, fmaf(sy[i], qy, sx[i] * qx));
    float score = (2.0f * inner - qn) - sn[i];
    unsigned u = __float_as_uint(score);
    u ^= (unsigned)((int)u >> 31) | 0x80000000u;
    unsigned long long nk = ((unsigned long long)u << 32) | (unsigned)(~i);
    if (nk > kv[K_ - 1]) {
#pragma unroll
      for (int j = K_ - 1; j >= 1; --j) {
        bool upPrev = nk > kv[j - 1];
        kv[j] = upPrev ? kv[j - 1] : ((nk > kv[j]) ? nk : kv[j]);
      }
      if (nk > kv[0]) kv[0] = nk;
    }
  }
#pragma unroll
  for (int j = 0; j < K_; ++j)
    knn_idx[((size_t)b * S_ + q) * K_ + j] = (int)(~(unsigned)kv[j]);
}

// ---------------------------------------------------------------------------
// MLP v2 (UNCHANGED -- verified, no spills).
// ---------------------------------------------------------------------------
#define W1S 76
#define W2S 132
#define CLS 72
#define HPS 132

__launch_bounds__(256, 1)
__global__ void mlp_kernel(const float* __restrict__ xyz,
                           const float* __restrict__ features,
                           const float* __restrict__ new_xyz,
                           const int* __restrict__ knn_idx,
                           const float* __restrict__ W1,
                           const float* __restrict__ b1,
                           const float* __restrict__ gamma,
                           const float* __restrict__ beta,
                           const float* __restrict__ W2,
                           const float* __restrict__ b2,
                           float* __restrict__ out_feat) {
  __shared__ float w1T[O_][W1S];
  __shared__ float w2T[O_][W2S];
  __shared__ float c_l[K_][CLS];
  __shared__ float hp[K_][HPS];
  __shared__ float pmaxl[8][O_];

  const int t = threadIdx.x;
  const int g = t >> 5;
  const int cg = t & 31;

  for (int e = t; e < CK_ * O_; e += 256) {
    int k = e >> 7, c = e & (O_ - 1);
    w1T[c][k] = W1[e];
  }
  if (t < O_) {
#pragma unroll
    for (int k = CK_; k < 68; ++k) w1T[t][k] = 0.0f;
  }
  for (int e = t; e < O_ * O_; e += 256) {
    int k = e >> 7, c = e & (O_ - 1);
    w2T[c][k] = W2[e];
  }
  float bb1[4], gm[4], bt[4], bb2 = 0.0f;
#pragma unroll
  for (int j = 0; j < 4; ++j) {
    bb1[j] = b1[cg + 32 * j];
    gm[j] = gamma[cg + 32 * j];
    bt[j] = beta[cg + 32 * j];
  }
  if (t < O_) bb2 = b2[t];

  const int bs0 = blockIdx.x * 64;
  const int b = bs0 >> 12;
  const float* fb = features + (size_t)b * N_ * C_;
  const float* xb = xyz + (size_t)b * N_ * 3;

  __syncthreads();

  for (int is = 0; is < 64; ++is) {
    const int bs = bs0 + is;
    const float qx = new_xyz[(size_t)bs * 3 + 0];
    const float qy = new_xyz[(size_t)bs * 3 + 1];
    const float qz = new_xyz[(size_t)bs * 3 + 2];

    for (int e = t; e < K_ * 68; e += 256) {
      int r = e / 68;
      int k = e - r * 68;
      int nbi = knn_idx[(size_t)bs * K_ + r];
      float v;
      if (k < C_) {
        v = fb[(size_t)nbi * C_ + k];
      } else if (k < CK_) {
        float coord = xb[nbi * 3 + (k - C_)];
        float qq = (k == C_) ? qx : ((k == C_ + 1) ? qy : qz);
        v = coord - qq;
      } else {
        v = 0.0f;
      }
      c_l[r][k] = v;
    }
    __syncthreads();

    float h[4][4];
#pragma unroll
    for (int i = 0; i < 4; ++i)
#pragma unroll
      for (int j = 0; j < 4; ++j) h[i][j] = 0.0f;
#pragma unroll
    for (int kc = 0; kc < 17; ++kc) {
      float4 w[4], a[4];
#pragma unroll
      for (int j = 0; j < 4; ++j)
        w[j] = *reinterpret_cast<const float4*>(&w1T[cg + 32 * j][kc * 4]);
#pragma unroll
      for (int i = 0; i < 4; ++i)
        a[i] = *reinterpret_cast<const float4*>(&c_l[4 * g + i][kc * 4]);
#pragma unroll
      for (int i = 0; i < 4; ++i)
#pragma unroll
        for (int j = 0; j < 4; ++j) {
          h[i][j] = fmaf(a[i].x, w[j].x, h[i][j]);
          h[i][j] = fmaf(a[i].y, w[j].y, h[i][j]);
          h[i][j] = fmaf(a[i].z, w[j].z, h[i][j]);
          h[i][j] = fmaf(a[i].w, w[j].w, h[i][j]);
        }
    }
#pragma unroll
    for (int i = 0; i < 4; ++i)
#pragma unroll
      for (int j = 0; j < 4; ++j) h[i][j] += bb1[j];

#pragma unroll
    for (int i = 0; i < 4; ++i) {
      float s1 = (h[i][0] + h[i][1]) + (h[i][2] + h[i][3]);
      float s2 = ((h[i][0] * h[i][0] + h[i][1] * h[i][1]) +
                  (h[i][2] * h[i][2] + h[i][3] * h[i][3]));
#pragma unroll
      for (int off = 1; off <= 16; off <<= 1) {
        s1 += __shfl_xor(s1, off);
        s2 += __shfl_xor(s2, off);
      }
      float mu = s1 * (1.0f / 128.0f);
      float va = fmaf(mu, -mu, s2 * (1.0f / 128.0f));
      float rs = rsqrtf(va + 1e-5f);
#pragma unroll
      for (int j = 0; j < 4; ++j) {
        float hv = fmaf((h[i][j] - mu) * rs, gm[j], bt[j]);
        hp[4 * g + i][cg + 32 * j] = fmaxf(hv, 0.0f);
      }
    }
    __syncthreads();

    float acc[4][4];
#pragma unroll
    for (int i = 0; i < 4; ++i)
#pragma unroll
      for (int j = 0; j < 4; ++j) acc[i][j] = 0.0f;
#pragma unroll 8
    for (int kc = 0; kc < 32; ++kc) {
      float4 w[4], a[4];
#pragma unroll
      for (int j = 0; j < 4; ++j)
        w[j] = *reinterpret_cast<const float4*>(&w2T[cg + 32 * j][kc * 4]);
#pragma unroll
      for (int i = 0; i < 4; ++i)
        a[i] = *reinterpret_cast<const float4*>(&hp[4 * g + i][kc * 4]);
#pragma unroll
      for (int i = 0; i < 4; ++i)
#pragma unroll
        for (int j = 0; j < 4; ++j) {
          acc[i][j] = fmaf(a[i].x, w[j].x, acc[i][j]);
          acc[i][j] = fmaf(a[i].y, w[j].y, acc[i][j]);
          acc[i][j] = fmaf(a[i].z, w[j].z, acc[i][j]);
          acc[i][j] = fmaf(a[i].w, w[j].w, acc[i][j]);
        }
    }
#pragma unroll
    for (int j = 0; j < 4; ++j) {
      float pm = fmaxf(fmaxf(acc[0][j], acc[1][j]), fmaxf(acc[2][j], acc[3][j]));
      pmaxl[g][cg + 32 * j] = pm;
    }
    __syncthreads();

    if (t < O_) {
      float m = pmaxl[0][t];
#pragma unroll
      for (int w = 1; w < 8; ++w) m = fmaxf(m, pmaxl[w][t]);
      out_feat[(size_t)bs * O_ + t] = m + bb2;
    }
    __syncthreads();
  }
}

extern "C" void kernel_launch(void* const* d_in, const int* in_sizes, int n_in,
                              void* d_out, int out_size, void* d_ws, size_t ws_size,
                              hipStream_t stream) {
  const float* xyz      = (const float*)d_in[0];
  const float* features = (const float*)d_in[1];
  const float* W1       = (const float*)d_in[2];
  const float* b1       = (const float*)d_in[3];
  const float* gamma    = (const float*)d_in[4];
  const float* beta     = (const float*)d_in[5];
  const float* W2       = (const float*)d_in[6];
  const float* b2       = (const float*)d_in[7];

  float* out      = (float*)d_out;
  float* new_xyz  = out;                          // [4,4096,3]
  float* new_feat = out + (size_t)B_ * S_ * 3;    // [4,4096,128]
  int* knn_idx = (int*)d_ws;                      // [4,4096,32] = 2 MB
  float4* sorted = (float4*)((char*)d_ws + (size_t)B_ * S_ * K_ * 4);  // 1 MB

  sort_kernel<<<B_, 1024, 0, stream>>>(xyz, sorted);
  fps_kernel<<<B_, 1024, 0, stream>>>(xyz, sorted, new_xyz);
  knn_kernel<<<dim3(S_ / 256, B_), 256, 0, stream>>>(new_xyz, knn_idx);
  mlp_kernel<<<B_ * S_ / 64, 256, 0, stream>>>(xyz, features, new_xyz, knn_idx,
                                               W1, b1, gamma, beta, W2, b2,
                                               new_feat);
}

// Round 6
// 24927.490 us; speedup vs baseline: 1.1120x; 1.1120x over previous
//
#include <hip/hip_runtime.h>
#include <cstdint>

typedef unsigned long long ull;

#define B_ 4
#define N_ 16384
#define C_ 64
#define O_ 128
#define S_ 4096
#define K_ 32
#define CK_ 67  // C+3

// ---------------------------------------------------------------------------
// Counting sort by 16^3 Morton cell (UNCHANGED -- verified rounds 4/5).
// ---------------------------------------------------------------------------
__device__ __forceinline__ unsigned part3_4(unsigned v) {
  return (v & 1u) | ((v & 2u) << 2) | ((v & 4u) << 4) | ((v & 8u) << 6);
}

__launch_bounds__(1024, 1)
__global__ void sort_kernel(const float* __restrict__ xyz,
                            float4* __restrict__ sorted) {
  const int b = blockIdx.x, t = threadIdx.x;
  const int lane = t & 63, wid = t >> 6;
  __shared__ unsigned hist[4096];
  __shared__ unsigned wsum[16];
  for (int i = t; i < 4096; i += 1024) hist[i] = 0u;
  __syncthreads();
  const float* base = xyz + (size_t)b * N_ * 3;
  int cell[16];
#pragma unroll
  for (int j = 0; j < 16; ++j) {
    int p = j * 1024 + t;
    float x = base[p * 3 + 0], y = base[p * 3 + 1], z = base[p * 3 + 2];
    int cx = (int)floorf((x + 6.0f) * (16.0f / 12.0f));
    int cy = (int)floorf((y + 6.0f) * (16.0f / 12.0f));
    int cz = (int)floorf((z + 6.0f) * (16.0f / 12.0f));
    cx = min(max(cx, 0), 15); cy = min(max(cy, 0), 15); cz = min(max(cz, 0), 15);
    int m = (int)(part3_4((unsigned)cx) | (part3_4((unsigned)cy) << 1) |
                  (part3_4((unsigned)cz) << 2));
    cell[j] = m;
    atomicAdd(&hist[m], 1u);
  }
  __syncthreads();
  unsigned h0 = hist[4 * t + 0], h1 = hist[4 * t + 1];
  unsigned h2 = hist[4 * t + 2], h3 = hist[4 * t + 3];
  unsigned s4 = h0 + h1 + h2 + h3;
  unsigned inc = s4;
#pragma unroll
  for (int off = 1; off < 64; off <<= 1) {
    unsigned n = __shfl_up(inc, off);
    if (lane >= off) inc += n;
  }
  if (lane == 63) wsum[wid] = inc;
  __syncthreads();
  if (t < 16) {
    unsigned v = wsum[t], iv = v;
#pragma unroll
    for (int off = 1; off < 16; off <<= 1) {
      unsigned n = __shfl_up(iv, off);
      if (t >= off) iv += n;
    }
    wsum[t] = iv - v;
  }
  __syncthreads();
  unsigned st = wsum[wid] + (inc - s4);
  hist[4 * t + 0] = st;
  hist[4 * t + 1] = st + h0;
  hist[4 * t + 2] = st + h0 + h1;
  hist[4 * t + 3] = st + h0 + h1 + h2;
  __syncthreads();
#pragma unroll
  for (int j = 0; j < 16; ++j) {
    int p = j * 1024 + t;
    float x = base[p * 3 + 0], y = base[p * 3 + 1], z = base[p * 3 + 2];
    unsigned pos = atomicAdd(&hist[cell[j]], 1u);
    float4 o;
    o.x = x; o.y = y; o.z = z; o.w = __uint_as_float((unsigned)p);
    sorted[(size_t)b * N_ + pos] = o;
  }
}

// ---------------------------------------------------------------------------
// FPS v5: 512 thr x 32 sorted pts/thread. Coords stay in GLOBAL (L2-resident
// 256KB/batch) -> persistent reg state is only dist[32]+AABB+key (~70 VGPR,
// no spill). Per-lane AABB skip (validated r4/r5); execz auto-skips waves
// whose 64 cells all skip. Round-3 verified sync skeleton: always-run u64
// shuffle, winner-lane writes key+coords to double-buffered LDS, ONE barrier,
// redundant 8-slot scan. Distance expr byte-identical to verified rounds.
// ---------------------------------------------------------------------------
__launch_bounds__(512, 1)
__global__ void fps_kernel(const float* __restrict__ xyz,
                           const float4* __restrict__ sorted,
                           float* __restrict__ new_xyz) {
#pragma clang fp contract(off)
  const int b = blockIdx.x, t = threadIdx.x;
  const int wid = t >> 6;  // 8 waves
  const float4* sb = sorted + (size_t)b * N_;
  float dist[32];
  float lox, hix, loy, hiy, loz, hiz;
  {
    float4 v0 = sb[32 * t];
    lox = hix = v0.x; loy = hiy = v0.y; loz = hiz = v0.z;
#pragma unroll
    for (int j = 1; j < 32; ++j) {
      float4 v = sb[32 * t + j];
      lox = fminf(lox, v.x); hix = fmaxf(hix, v.x);
      loy = fminf(loy, v.y); hiy = fmaxf(hiy, v.y);
      loz = fminf(loz, v.z); hiz = fmaxf(hiz, v.z);
    }
  }
#pragma unroll
  for (int j = 0; j < 32; ++j) dist[j] = 1e10f;
  __shared__ ull s_key[2][8];
  __shared__ float s_cd[2][8][3];
  const float* ob = xyz + (size_t)b * N_ * 3;
  float fx = ob[0], fy = ob[1], fz = ob[2];  // far = 0 initially
  ull mykey = ((ull)__float_as_uint(1e10f)) << 28;  // bmax=1e10 -> no skip at s=0
  float mybx = 0.f, myby = 0.f, mybz = 0.f;
  for (int s = 0; s < S_; ++s) {
    const int buf = s & 1;
    if (t == 0) {
      float* o = new_xyz + ((size_t)b * S_ + s) * 3;
      o[0] = fx; o[1] = fy; o[2] = fz;
    }
    float dxm = fmaxf(fmaxf(lox - fx, fx - hix), 0.0f);
    float dym = fmaxf(fmaxf(loy - fy, fy - hiy), 0.0f);
    float dzm = fmaxf(fmaxf(loz - fz, fz - hiz), 0.0f);
    float lb = dxm * dxm + dym * dym + dzm * dzm;
    float bmax = __uint_as_float((unsigned)(mykey >> 28));
    if (lb * 0.99998f < bmax) {  // conservative skip (covers f32 rounding)
      float bv = -1.0f;
      unsigned bo = 0xFFFFFFFFu;
      int bp = 0;
      float bx = 0.f, by = 0.f, bz = 0.f;
#pragma unroll
      for (int j = 0; j < 32; ++j) {
        float4 v = sb[32 * t + j];  // L2-hot
        float dx = v.x - fx;
        float dy = v.y - fy;
        float dz = v.z - fz;
        float d = dx * dx + dy * dy + dz * dz;  // contract off, verified form
        float m = fminf(dist[j], d);
        dist[j] = m;
        unsigned og = __float_as_uint(v.w);
        bool better = (m > bv) || ((m == bv) && (og < bo));
        if (better) { bv = m; bo = og; bp = j; bx = v.x; by = v.y; bz = v.z; }
      }
      mykey = (((ull)__float_as_uint(bv)) << 28) |
              (((ull)((~bo) & 0x3FFFu)) << 14) | (unsigned)(32 * t + bp);
      mybx = bx; myby = by; mybz = bz;
    }
    ull k = mykey;
#pragma unroll
    for (int off = 1; off < 64; off <<= 1) {
      ull o = __shfl_xor(k, off);
      if (o > k) k = o;
    }
    if (k == mykey) {  // exactly one lane (pos bits unique); stale-but-valid ok
      s_key[buf][wid] = k;
      s_cd[buf][wid][0] = mybx; s_cd[buf][wid][1] = myby; s_cd[buf][wid][2] = mybz;
    }
    __syncthreads();
    ull kb = s_key[buf][0];
    int bw = 0;
#pragma unroll
    for (int w = 1; w < 8; ++w) {
      ull o = s_key[buf][w];
      if (o > kb) { kb = o; bw = w; }
    }
    fx = s_cd[buf][bw][0]; fy = s_cd[buf][bw][1]; fz = s_cd[buf][bw][2];
  }
}

// ---------------------------------------------------------------------------
// KNN over new_xyz (UNCHANGED -- verified).
// ---------------------------------------------------------------------------
__launch_bounds__(256, 2)
__global__ void knn_kernel(const float* __restrict__ new_xyz,
                           int* __restrict__ knn_idx) {
  const int b = blockIdx.y;
  const int t = threadIdx.x;
  const int q = blockIdx.x * 256 + t;
  __shared__ float sx[S_], sy[S_], sz[S_], sn[S_];
  const float* nb = new_xyz + (size_t)b * S_ * 3;
  for (int i = t; i < S_; i += 256) {
    float x = nb[i * 3 + 0], y = nb[i * 3 + 1], z = nb[i * 3 + 2];
    sx[i] = x; sy[i] = y; sz[i] = z;
    sn[i] = fmaf(z, z, fmaf(y, y, x * x));
  }
  __syncthreads();
  const float qx = sx[q], qy = sy[q], qz = sz[q], qn = sn[q];
  unsigned long long kv[K_];
#pragma unroll
  for (int j = 0; j < K_; ++j) kv[j] = 0ull;
  for (int i = 0; i < S_; ++i) {
    float inner = fmaf(sz[i], qz, fmaf(sy[i], qy, sx[i] * qx));
    float score = (2.0f * inner - qn) - sn[i];
    unsigned u = __float_as_uint(score);
    u ^= (unsigned)((int)u >> 31) | 0x80000000u;
    unsigned long long nk = ((unsigned long long)u << 32) | (unsigned)(~i);
    if (nk > kv[K_ - 1]) {
#pragma unroll
      for (int j = K_ - 1; j >= 1; --j) {
        bool upPrev = nk > kv[j - 1];
        kv[j] = upPrev ? kv[j - 1] : ((nk > kv[j]) ? nk : kv[j]);
      }
      if (nk > kv[0]) kv[0] = nk;
    }
  }
#pragma unroll
  for (int j = 0; j < K_; ++j)
    knn_idx[((size_t)b * S_ + q) * K_ + j] = (int)(~(unsigned)kv[j]);
}

// ---------------------------------------------------------------------------
// MLP v2 (UNCHANGED -- verified, no spills).
// ---------------------------------------------------------------------------
#define W1S 76
#define W2S 132
#define CLS 72
#define HPS 132

__launch_bounds__(256, 1)
__global__ void mlp_kernel(const float* __restrict__ xyz,
                           const float* __restrict__ features,
                           const float* __restrict__ new_xyz,
                           const int* __restrict__ knn_idx,
                           const float* __restrict__ W1,
                           const float* __restrict__ b1,
                           const float* __restrict__ gamma,
                           const float* __restrict__ beta,
                           const float* __restrict__ W2,
                           const float* __restrict__ b2,
                           float* __restrict__ out_feat) {
  __shared__ float w1T[O_][W1S];
  __shared__ float w2T[O_][W2S];
  __shared__ float c_l[K_][CLS];
  __shared__ float hp[K_][HPS];
  __shared__ float pmaxl[8][O_];

  const int t = threadIdx.x;
  const int g = t >> 5;
  const int cg = t & 31;

  for (int e = t; e < CK_ * O_; e += 256) {
    int k = e >> 7, c = e & (O_ - 1);
    w1T[c][k] = W1[e];
  }
  if (t < O_) {
#pragma unroll
    for (int k = CK_; k < 68; ++k) w1T[t][k] = 0.0f;
  }
  for (int e = t; e < O_ * O_; e += 256) {
    int k = e >> 7, c = e & (O_ - 1);
    w2T[c][k] = W2[e];
  }
  float bb1[4], gm[4], bt[4], bb2 = 0.0f;
#pragma unroll
  for (int j = 0; j < 4; ++j) {
    bb1[j] = b1[cg + 32 * j];
    gm[j] = gamma[cg + 32 * j];
    bt[j] = beta[cg + 32 * j];
  }
  if (t < O_) bb2 = b2[t];

  const int bs0 = blockIdx.x * 64;
  const int b = bs0 >> 12;
  const float* fb = features + (size_t)b * N_ * C_;
  const float* xb = xyz + (size_t)b * N_ * 3;

  __syncthreads();

  for (int is = 0; is < 64; ++is) {
    const int bs = bs0 + is;
    const float qx = new_xyz[(size_t)bs * 3 + 0];
    const float qy = new_xyz[(size_t)bs * 3 + 1];
    const float qz = new_xyz[(size_t)bs * 3 + 2];

    for (int e = t; e < K_ * 68; e += 256) {
      int r = e / 68;
      int k = e - r * 68;
      int nbi = knn_idx[(size_t)bs * K_ + r];
      float v;
      if (k < C_) {
        v = fb[(size_t)nbi * C_ + k];
      } else if (k < CK_) {
        float coord = xb[nbi * 3 + (k - C_)];
        float qq = (k == C_) ? qx : ((k == C_ + 1) ? qy : qz);
        v = coord - qq;
      } else {
        v = 0.0f;
      }
      c_l[r][k] = v;
    }
    __syncthreads();

    float h[4][4];
#pragma unroll
    for (int i = 0; i < 4; ++i)
#pragma unroll
      for (int j = 0; j < 4; ++j) h[i][j] = 0.0f;
#pragma unroll
    for (int kc = 0; kc < 17; ++kc) {
      float4 w[4], a[4];
#pragma unroll
      for (int j = 0; j < 4; ++j)
        w[j] = *reinterpret_cast<const float4*>(&w1T[cg + 32 * j][kc * 4]);
#pragma unroll
      for (int i = 0; i < 4; ++i)
        a[i] = *reinterpret_cast<const float4*>(&c_l[4 * g + i][kc * 4]);
#pragma unroll
      for (int i = 0; i < 4; ++i)
#pragma unroll
        for (int j = 0; j < 4; ++j) {
          h[i][j] = fmaf(a[i].x, w[j].x, h[i][j]);
          h[i][j] = fmaf(a[i].y, w[j].y, h[i][j]);
          h[i][j] = fmaf(a[i].z, w[j].z, h[i][j]);
          h[i][j] = fmaf(a[i].w, w[j].w, h[i][j]);
        }
    }
#pragma unroll
    for (int i = 0; i < 4; ++i)
#pragma unroll
      for (int j = 0; j < 4; ++j) h[i][j] += bb1[j];

#pragma unroll
    for (int i = 0; i < 4; ++i) {
      float s1 = (h[i][0] + h[i][1]) + (h[i][2] + h[i][3]);
      float s2 = ((h[i][0] * h[i][0] + h[i][1] * h[i][1]) +
                  (h[i][2] * h[i][2] + h[i][3] * h[i][3]));
#pragma unroll
      for (int off = 1; off <= 16; off <<= 1) {
        s1 += __shfl_xor(s1, off);
        s2 += __shfl_xor(s2, off);
      }
      float mu = s1 * (1.0f / 128.0f);
      float va = fmaf(mu, -mu, s2 * (1.0f / 128.0f));
      float rs = rsqrtf(va + 1e-5f);
#pragma unroll
      for (int j = 0; j < 4; ++j) {
        float hv = fmaf((h[i][j] - mu) * rs, gm[j], bt[j]);
        hp[4 * g + i][cg + 32 * j] = fmaxf(hv, 0.0f);
      }
    }
    __syncthreads();

    float acc[4][4];
#pragma unroll
    for (int i = 0; i < 4; ++i)
#pragma unroll
      for (int j = 0; j < 4; ++j) acc[i][j] = 0.0f;
#pragma unroll 8
    for (int kc = 0; kc < 32; ++kc) {
      float4 w[4], a[4];
#pragma unroll
      for (int j = 0; j < 4; ++j)
        w[j] = *reinterpret_cast<const float4*>(&w2T[cg + 32 * j][kc * 4]);
#pragma unroll
      for (int i = 0; i < 4; ++i)
        a[i] = *reinterpret_cast<const float4*>(&hp[4 * g + i][kc * 4]);
#pragma unroll
      for (int i = 0; i < 4; ++i)
#pragma unroll
        for (int j = 0; j < 4; ++j) {
          acc[i][j] = fmaf(a[i].x, w[j].x, acc[i][j]);
          acc[i][j] = fmaf(a[i].y, w[j].y, acc[i][j]);
          acc[i][j] = fmaf(a[i].z, w[j].z, acc[i][j]);
          acc[i][j] = fmaf(a[i].w, w[j].w, acc[i][j]);
        }
    }
#pragma unroll
    for (int j = 0; j < 4; ++j) {
      float pm = fmaxf(fmaxf(acc[0][j], acc[1][j]), fmaxf(acc[2][j], acc[3][j]));
      pmaxl[g][cg + 32 * j] = pm;
    }
    __syncthreads();

    if (t < O_) {
      float m = pmaxl[0][t];
#pragma unroll
      for (int w = 1; w < 8; ++w) m = fmaxf(m, pmaxl[w][t]);
      out_feat[(size_t)bs * O_ + t] = m + bb2;
    }
    __syncthreads();
  }
}

extern "C" void kernel_launch(void* const* d_in, const int* in_sizes, int n_in,
                              void* d_out, int out_size, void* d_ws, size_t ws_size,
                              hipStream_t stream) {
  const float* xyz      = (const float*)d_in[0];
  const float* features = (const float*)d_in[1];
  const float* W1       = (const float*)d_in[2];
  const float* b1       = (const float*)d_in[3];
  const float* gamma    = (const float*)d_in[4];
  const float* beta     = (const float*)d_in[5];
  const float* W2       = (const float*)d_in[6];
  const float* b2       = (const float*)d_in[7];

  float* out      = (float*)d_out;
  float* new_xyz  = out;                          // [4,4096,3]
  float* new_feat = out + (size_t)B_ * S_ * 3;    // [4,4096,128]
  int* knn_idx = (int*)d_ws;                      // [4,4096,32] = 2 MB
  float4* sorted = (float4*)((char*)d_ws + (size_t)B_ * S_ * K_ * 4);  // 1 MB

  sort_kernel<<<B_, 1024, 0, stream>>>(xyz, sorted);
  fps_kernel<<<B_, 512, 0, stream>>>(xyz, sorted, new_xyz);
  knn_kernel<<<dim3(S_ / 256, B_), 256, 0, stream>>>(new_xyz, knn_idx);
  mlp_kernel<<<B_ * S_ / 64, 256, 0, stream>>>(xyz, features, new_xyz, knn_idx,
                                               W1, b1, gamma, beta, W2, b2,
                                               new_feat);
}

// Round 7
// 16718.500 us; speedup vs baseline: 1.6581x; 1.4910x over previous
//
#include <hip/hip_runtime.h>
#include <cstdint>

typedef unsigned long long ull;

#define B_ 4
#define N_ 16384
#define C_ 64
#define O_ 128
#define S_ 4096
#define K_ 32
#define CK_ 67  // C+3

// ---------------------------------------------------------------------------
// Counting sort by 16^3 Morton cell (UNCHANGED -- verified rounds 4/5/6).
// ---------------------------------------------------------------------------
__device__ __forceinline__ unsigned part3_4(unsigned v) {
  return (v & 1u) | ((v & 2u) << 2) | ((v & 4u) << 4) | ((v & 8u) << 6);
}

__launch_bounds__(1024, 1)
__global__ void sort_kernel(const float* __restrict__ xyz,
                            float4* __restrict__ sorted) {
  const int b = blockIdx.x, t = threadIdx.x;
  const int lane = t & 63, wid = t >> 6;
  __shared__ unsigned hist[4096];
  __shared__ unsigned wsum[16];
  for (int i = t; i < 4096; i += 1024) hist[i] = 0u;
  __syncthreads();
  const float* base = xyz + (size_t)b * N_ * 3;
  int cell[16];
#pragma unroll
  for (int j = 0; j < 16; ++j) {
    int p = j * 1024 + t;
    float x = base[p * 3 + 0], y = base[p * 3 + 1], z = base[p * 3 + 2];
    int cx = (int)floorf((x + 6.0f) * (16.0f / 12.0f));
    int cy = (int)floorf((y + 6.0f) * (16.0f / 12.0f));
    int cz = (int)floorf((z + 6.0f) * (16.0f / 12.0f));
    cx = min(max(cx, 0), 15); cy = min(max(cy, 0), 15); cz = min(max(cz, 0), 15);
    int m = (int)(part3_4((unsigned)cx) | (part3_4((unsigned)cy) << 1) |
                  (part3_4((unsigned)cz) << 2));
    cell[j] = m;
    atomicAdd(&hist[m], 1u);
  }
  __syncthreads();
  unsigned h0 = hist[4 * t + 0], h1 = hist[4 * t + 1];
  unsigned h2 = hist[4 * t + 2], h3 = hist[4 * t + 3];
  unsigned s4 = h0 + h1 + h2 + h3;
  unsigned inc = s4;
#pragma unroll
  for (int off = 1; off < 64; off <<= 1) {
    unsigned n = __shfl_up(inc, off);
    if (lane >= off) inc += n;
  }
  if (lane == 63) wsum[wid] = inc;
  __syncthreads();
  if (t < 16) {
    unsigned v = wsum[t], iv = v;
#pragma unroll
    for (int off = 1; off < 16; off <<= 1) {
      unsigned n = __shfl_up(iv, off);
      if (t >= off) iv += n;
    }
    wsum[t] = iv - v;
  }
  __syncthreads();
  unsigned st = wsum[wid] + (inc - s4);
  hist[4 * t + 0] = st;
  hist[4 * t + 1] = st + h0;
  hist[4 * t + 2] = st + h0 + h1;
  hist[4 * t + 3] = st + h0 + h1 + h2;
  __syncthreads();
#pragma unroll
  for (int j = 0; j < 16; ++j) {
    int p = j * 1024 + t;
    float x = base[p * 3 + 0], y = base[p * 3 + 1], z = base[p * 3 + 2];
    unsigned pos = atomicAdd(&hist[cell[j]], 1u);
    float4 o;
    o.x = x; o.y = y; o.z = z; o.w = __uint_as_float((unsigned)p);
    sorted[(size_t)b * N_ + pos] = o;
  }
}

// ---------------------------------------------------------------------------
// FPS v6: 512 thr x 32 sorted pts. Lazy skip (validated r4-r6) + latency fixes:
//  - update loop loads ALL 32 float4 into registers first (one vmcnt wait),
//  - u64-key TREE argmax (depth 5) instead of 32-deep select chain,
//  - skipped waves forward wkey (no shuffle); updating waves do 6-lvl shuffle,
//  - no coord tracking: block winner coords re-fetched sb[pos] (L1-hot).
// Exactness: skipped bucket's dists untouched -> stored key stays the exact
// bucket max; distance expr byte-identical to verified rounds; key =
// dist|~og|pos gives (value desc, orig-idx asc) == jnp.argmax semantics.
// ---------------------------------------------------------------------------
__launch_bounds__(512)
__global__ void fps_kernel(const float* __restrict__ xyz,
                           const float4* __restrict__ sorted,
                           float* __restrict__ new_xyz) {
#pragma clang fp contract(off)
  const int b = blockIdx.x, t = threadIdx.x;
  const int lane = t & 63, wid = t >> 6;  // 8 waves
  const float4* sb = sorted + (size_t)b * N_;
  float dist[32];
  float lox, hix, loy, hiy, loz, hiz;
  {
    float4 v0 = sb[32 * t];
    lox = hix = v0.x; loy = hiy = v0.y; loz = hiz = v0.z;
#pragma unroll
    for (int j = 1; j < 32; ++j) {
      float4 v = sb[32 * t + j];
      lox = fminf(lox, v.x); hix = fmaxf(hix, v.x);
      loy = fminf(loy, v.y); hiy = fmaxf(hiy, v.y);
      loz = fminf(loz, v.z); hiz = fmaxf(hiz, v.z);
    }
  }
#pragma unroll
  for (int j = 0; j < 32; ++j) dist[j] = 1e10f;
  __shared__ ull s_key[2][8];
  const float* ob = xyz + (size_t)b * N_ * 3;
  float fx = ob[0], fy = ob[1], fz = ob[2];  // far = 0 initially
  ull mykey = ((ull)__float_as_uint(1e10f)) << 28;  // bmax=1e10 -> all update s=0
  ull wkey = 0;  // wave-uniform best; set at s=0 (all waves update then)
  for (int s = 0; s < S_; ++s) {
    const int buf = s & 1;
    if (t == 0) {
      float* o = new_xyz + ((size_t)b * S_ + s) * 3;
      o[0] = fx; o[1] = fy; o[2] = fz;
    }
    float dxm = fmaxf(fmaxf(lox - fx, fx - hix), 0.0f);
    float dym = fmaxf(fmaxf(loy - fy, fy - hiy), 0.0f);
    float dzm = fmaxf(fmaxf(loz - fz, fz - hiz), 0.0f);
    float lb = dxm * dxm + dym * dym + dzm * dzm;
    float bmax = __uint_as_float((unsigned)(mykey >> 28));
    bool upd = (lb * 0.99998f < bmax);  // conservative (covers f32 rounding)
    if (__any(upd)) {
      if (upd) {
        float4 vb[32];
#pragma unroll
        for (int j = 0; j < 32; ++j) vb[j] = sb[32 * t + j];  // batched: 1 wait
        ull kj[32];
#pragma unroll
        for (int j = 0; j < 32; ++j) {
          float dx = vb[j].x - fx;
          float dy = vb[j].y - fy;
          float dz = vb[j].z - fz;
          float d = dx * dx + dy * dy + dz * dz;  // contract off, verified form
          float m = fminf(dist[j], d);
          dist[j] = m;
          unsigned og = __float_as_uint(vb[j].w);
          kj[j] = (((ull)__float_as_uint(m)) << 28) |
                  (((ull)((~og) & 0x3FFFu)) << 14) | (unsigned)(32 * t + j);
        }
#pragma unroll
        for (int stp = 16; stp >= 1; stp >>= 1)
#pragma unroll
          for (int j = 0; j < stp; ++j)
            if (kj[j + stp] > kj[j]) kj[j] = kj[j + stp];
        mykey = kj[0];
      }
      ull k = mykey;
#pragma unroll
      for (int off = 1; off < 64; off <<= 1) {
        ull o = __shfl_xor(k, off);
        if (o > k) k = o;
      }
      wkey = k;
    }
    if (lane == 0) s_key[buf][wid] = wkey;
    __syncthreads();
    ull kb = s_key[buf][0];
#pragma unroll
    for (int w = 1; w < 8; ++w) {
      ull o = s_key[buf][w];
      if (o > kb) kb = o;
    }
    float4 c = sb[(unsigned)(kb & 0x3FFFu)];  // uniform addr, L1-hot
    fx = c.x; fy = c.y; fz = c.z;
  }
}

// ---------------------------------------------------------------------------
// KNN over new_xyz (UNCHANGED -- verified).
// ---------------------------------------------------------------------------
__launch_bounds__(256, 2)
__global__ void knn_kernel(const float* __restrict__ new_xyz,
                           int* __restrict__ knn_idx) {
  const int b = blockIdx.y;
  const int t = threadIdx.x;
  const int q = blockIdx.x * 256 + t;
  __shared__ float sx[S_], sy[S_], sz[S_], sn[S_];
  const float* nb = new_xyz + (size_t)b * S_ * 3;
  for (int i = t; i < S_; i += 256) {
    float x = nb[i * 3 + 0], y = nb[i * 3 + 1], z = nb[i * 3 + 2];
    sx[i] = x; sy[i] = y; sz[i] = z;
    sn[i] = fmaf(z, z, fmaf(y, y, x * x));
  }
  __syncthreads();
  const float qx = sx[q], qy = sy[q], qz = sz[q], qn = sn[q];
  unsigned long long kv[K_];
#pragma unroll
  for (int j = 0; j < K_; ++j) kv[j] = 0ull;
  for (int i = 0; i < S_; ++i) {
    float inner = fmaf(sz[i], qz, fmaf(sy[i], qy, sx[i] * qx));
    float score = (2.0f * inner - qn) - sn[i];
    unsigned u = __float_as_uint(score);
    u ^= (unsigned)((int)u >> 31) | 0x80000000u;
    unsigned long long nk = ((unsigned long long)u << 32) | (unsigned)(~i);
    if (nk > kv[K_ - 1]) {
#pragma unroll
      for (int j = K_ - 1; j >= 1; --j) {
        bool upPrev = nk > kv[j - 1];
        kv[j] = upPrev ? kv[j - 1] : ((nk > kv[j]) ? nk : kv[j]);
      }
      if (nk > kv[0]) kv[0] = nk;
    }
  }
#pragma unroll
  for (int j = 0; j < K_; ++j)
    knn_idx[((size_t)b * S_ + q) * K_ + j] = (int)(~(unsigned)kv[j]);
}

// ---------------------------------------------------------------------------
// MLP v2 (UNCHANGED -- verified, no spills).
// ---------------------------------------------------------------------------
#define W1S 76
#define W2S 132
#define CLS 72
#define HPS 132

__launch_bounds__(256, 1)
__global__ void mlp_kernel(const float* __restrict__ xyz,
                           const float* __restrict__ features,
                           const float* __restrict__ new_xyz,
                           const int* __restrict__ knn_idx,
                           const float* __restrict__ W1,
                           const float* __restrict__ b1,
                           const float* __restrict__ gamma,
                           const float* __restrict__ beta,
                           const float* __restrict__ W2,
                           const float* __restrict__ b2,
                           float* __restrict__ out_feat) {
  __shared__ float w1T[O_][W1S];
  __shared__ float w2T[O_][W2S];
  __shared__ float c_l[K_][CLS];
  __shared__ float hp[K_][HPS];
  __shared__ float pmaxl[8][O_];

  const int t = threadIdx.x;
  const int g = t >> 5;
  const int cg = t & 31;

  for (int e = t; e < CK_ * O_; e += 256) {
    int k = e >> 7, c = e & (O_ - 1);
    w1T[c][k] = W1[e];
  }
  if (t < O_) {
#pragma unroll
    for (int k = CK_; k < 68; ++k) w1T[t][k] = 0.0f;
  }
  for (int e = t; e < O_ * O_; e += 256) {
    int k = e >> 7, c = e & (O_ - 1);
    w2T[c][k] = W2[e];
  }
  float bb1[4], gm[4], bt[4], bb2 = 0.0f;
#pragma unroll
  for (int j = 0; j < 4; ++j) {
    bb1[j] = b1[cg + 32 * j];
    gm[j] = gamma[cg + 32 * j];
    bt[j] = beta[cg + 32 * j];
  }
  if (t < O_) bb2 = b2[t];

  const int bs0 = blockIdx.x * 64;
  const int b = bs0 >> 12;
  const float* fb = features + (size_t)b * N_ * C_;
  const float* xb = xyz + (size_t)b * N_ * 3;

  __syncthreads();

  for (int is = 0; is < 64; ++is) {
    const int bs = bs0 + is;
    const float qx = new_xyz[(size_t)bs * 3 + 0];
    const float qy = new_xyz[(size_t)bs * 3 + 1];
    const float qz = new_xyz[(size_t)bs * 3 + 2];

    for (int e = t; e < K_ * 68; e += 256) {
      int r = e / 68;
      int k = e - r * 68;
      int nbi = knn_idx[(size_t)bs * K_ + r];
      float v;
      if (k < C_) {
        v = fb[(size_t)nbi * C_ + k];
      } else if (k < CK_) {
        float coord = xb[nbi * 3 + (k - C_)];
        float qq = (k == C_) ? qx : ((k == C_ + 1) ? qy : qz);
        v = coord - qq;
      } else {
        v = 0.0f;
      }
      c_l[r][k] = v;
    }
    __syncthreads();

    float h[4][4];
#pragma unroll
    for (int i = 0; i < 4; ++i)
#pragma unroll
      for (int j = 0; j < 4; ++j) h[i][j] = 0.0f;
#pragma unroll
    for (int kc = 0; kc < 17; ++kc) {
      float4 w[4], a[4];
#pragma unroll
      for (int j = 0; j < 4; ++j)
        w[j] = *reinterpret_cast<const float4*>(&w1T[cg + 32 * j][kc * 4]);
#pragma unroll
      for (int i = 0; i < 4; ++i)
        a[i] = *reinterpret_cast<const float4*>(&c_l[4 * g + i][kc * 4]);
#pragma unroll
      for (int i = 0; i < 4; ++i)
#pragma unroll
        for (int j = 0; j < 4; ++j) {
          h[i][j] = fmaf(a[i].x, w[j].x, h[i][j]);
          h[i][j] = fmaf(a[i].y, w[j].y, h[i][j]);
          h[i][j] = fmaf(a[i].z, w[j].z, h[i][j]);
          h[i][j] = fmaf(a[i].w, w[j].w, h[i][j]);
        }
    }
#pragma unroll
    for (int i = 0; i < 4; ++i)
#pragma unroll
      for (int j = 0; j < 4; ++j) h[i][j] += bb1[j];

#pragma unroll
    for (int i = 0; i < 4; ++i) {
      float s1 = (h[i][0] + h[i][1]) + (h[i][2] + h[i][3]);
      float s2 = ((h[i][0] * h[i][0] + h[i][1] * h[i][1]) +
                  (h[i][2] * h[i][2] + h[i][3] * h[i][3]));
#pragma unroll
      for (int off = 1; off <= 16; off <<= 1) {
        s1 += __shfl_xor(s1, off);
        s2 += __shfl_xor(s2, off);
      }
      float mu = s1 * (1.0f / 128.0f);
      float va = fmaf(mu, -mu, s2 * (1.0f / 128.0f));
      float rs = rsqrtf(va + 1e-5f);
#pragma unroll
      for (int j = 0; j < 4; ++j) {
        float hv = fmaf((h[i][j] - mu) * rs, gm[j], bt[j]);
        hp[4 * g + i][cg + 32 * j] = fmaxf(hv, 0.0f);
      }
    }
    __syncthreads();

    float acc[4][4];
#pragma unroll
    for (int i = 0; i < 4; ++i)
#pragma unroll
      for (int j = 0; j < 4; ++j) acc[i][j] = 0.0f;
#pragma unroll 8
    for (int kc = 0; kc < 32; ++kc) {
      float4 w[4], a[4];
#pragma unroll
      for (int j = 0; j < 4; ++j)
        w[j] = *reinterpret_cast<const float4*>(&w2T[cg + 32 * j][kc * 4]);
#pragma unroll
      for (int i = 0; i < 4; ++i)
        a[i] = *reinterpret_cast<const float4*>(&hp[4 * g + i][kc * 4]);
#pragma unroll
      for (int i = 0; i < 4; ++i)
#pragma unroll
        for (int j = 0; j < 4; ++j) {
          acc[i][j] = fmaf(a[i].x, w[j].x, acc[i][j]);
          acc[i][j] = fmaf(a[i].y, w[j].y, acc[i][j]);
          acc[i][j] = fmaf(a[i].z, w[j].z, acc[i][j]);
          acc[i][j] = fmaf(a[i].w, w[j].w, acc[i][j]);
        }
    }
#pragma unroll
    for (int j = 0; j < 4; ++j) {
      float pm = fmaxf(fmaxf(acc[0][j], acc[1][j]), fmaxf(acc[2][j], acc[3][j]));
      pmaxl[g][cg + 32 * j] = pm;
    }
    __syncthreads();

    if (t < O_) {
      float m = pmaxl[0][t];
#pragma unroll
      for (int w = 1; w < 8; ++w) m = fmaxf(m, pmaxl[w][t]);
      out_feat[(size_t)bs * O_ + t] = m + bb2;
    }
    __syncthreads();
  }
}

extern "C" void kernel_launch(void* const* d_in, const int* in_sizes, int n_in,
                              void* d_out, int out_size, void* d_ws, size_t ws_size,
                              hipStream_t stream) {
  const float* xyz      = (const float*)d_in[0];
  const float* features = (const float*)d_in[1];
  const float* W1       = (const float*)d_in[2];
  const float* b1       = (const float*)d_in[3];
  const float* gamma    = (const float*)d_in[4];
  const float* beta     = (const float*)d_in[5];
  const float* W2       = (const float*)d_in[6];
  const float* b2       = (const float*)d_in[7];

  float* out      = (float*)d_out;
  float* new_xyz  = out;                          // [4,4096,3]
  float* new_feat = out + (size_t)B_ * S_ * 3;    // [4,4096,128]
  int* knn_idx = (int*)d_ws;                      // [4,4096,32] = 2 MB
  float4* sorted = (float4*)((char*)d_ws + (size_t)B_ * S_ * K_ * 4);  // 1 MB

  sort_kernel<<<B_, 1024, 0, stream>>>(xyz, sorted);
  fps_kernel<<<B_, 512, 0, stream>>>(xyz, sorted, new_xyz);
  knn_kernel<<<dim3(S_ / 256, B_), 256, 0, stream>>>(new_xyz, knn_idx);
  mlp_kernel<<<B_ * S_ / 64, 256, 0, stream>>>(xyz, features, new_xyz, knn_idx,
                                               W1, b1, gamma, beta, W2, b2,
                                               new_feat);
}